// Round 1
// baseline (629.493 us; speedup 1.0000x reference)
//
// SlotAttention fused forward for MI355X (gfx950).
// Design: fold k/v projections into per-slot vectors u = (q@Wk)*g_f so each of the
// 3 iterations streams features exactly once (256MB). Big kernel computes per-n LN
// stats in registers, logits via 16x16x32 bf16 MFMA, softmax over slots via 16-lane
// shfl_xor, and P = sum_n (a*rs)*x via a second MFMA whose A-fragment is exactly the
// softmax C-fragment (row-interleaving trick). Small GEMV kernels do q-prep, Wv,
// GRU, and MLP.
#include <hip/hip_runtime.h>
#include <cstdint>
#include <cstddef>

#define BB    16
#define NTOK  16384
#define KS    16      // slots
#define DD    256
#define FEATN 256
#define NBLK  32      // blocks per batch in big kernel
#define LN_EPS 1e-5f

typedef float        float4v __attribute__((ext_vector_type(4)));
typedef unsigned int uint4v  __attribute__((ext_vector_type(4)));
typedef __bf16       bf16x8  __attribute__((ext_vector_type(8)));

// ---------------------------------------------------------------- stage 0: q/u/su/cb
__global__ void stage0_kernel(const float* __restrict__ slots,
                              const float* __restrict__ Wq, const float* __restrict__ Wk,
                              const float* __restrict__ g_s, const float* __restrict__ b_s,
                              const float* __restrict__ g_f, const float* __restrict__ b_f,
                              unsigned short* __restrict__ u_buf,
                              float* __restrict__ su_buf, float* __restrict__ cb_buf)
{
  const int b = blockIdx.x, tid = threadIdx.x;
  const int w = tid >> 6, lane = tid & 63;
  __shared__ float y[KS][DD];
  __shared__ float q[KS][DD];
  __shared__ float red[8];
  __shared__ float redsu[4][KS], redcb[4][KS];

  // LN(slots, g_s, b_s)
  for (int k = 0; k < KS; ++k) {
    const float v = slots[(size_t)(b*KS + k)*DD + tid];
    float s = v;
    #pragma unroll
    for (int m = 1; m < 64; m <<= 1) s += __shfl_xor(s, m);
    if (lane == 0) red[w] = s;
    __syncthreads();
    const float mean = (red[0]+red[1]+red[2]+red[3]) * (1.f/DD);
    const float dv = v - mean;
    float s2 = dv*dv;
    #pragma unroll
    for (int m = 1; m < 64; m <<= 1) s2 += __shfl_xor(s2, m);
    if (lane == 0) red[4+w] = s2;
    __syncthreads();
    const float var = (red[4]+red[5]+red[6]+red[7]) * (1.f/DD);
    y[k][tid] = dv * rsqrtf(var + LN_EPS) * g_s[tid] + b_s[tid];
    __syncthreads();
  }
  // q[k][d] = sum_c y[k][c] * Wq[d][c]
  {
    float acc[KS];
    #pragma unroll
    for (int k = 0; k < KS; ++k) acc[k] = 0.f;
    for (int cc = 0; cc < DD; ++cc) {
      const float wv = Wq[(size_t)tid*DD + cc];
      #pragma unroll
      for (int k = 0; k < KS; ++k) acc[k] += y[k][cc] * wv;
    }
    #pragma unroll
    for (int k = 0; k < KS; ++k) q[k][tid] = acc[k];
  }
  __syncthreads();
  // qk[k][c] = sum_d q[k][d] * Wk[d][c];  u = qk*g_f (bf16), su = sum u, cb = qk . b_f
  {
    float acc[KS];
    #pragma unroll
    for (int k = 0; k < KS; ++k) acc[k] = 0.f;
    for (int dd = 0; dd < DD; ++dd) {
      const float wv = Wk[(size_t)dd*DD + tid];
      #pragma unroll
      for (int k = 0; k < KS; ++k) acc[k] += q[k][dd] * wv;
    }
    const float gf = g_f[tid], bfv = b_f[tid];
    float sus[KS], cbs[KS];
    #pragma unroll
    for (int k = 0; k < KS; ++k) {
      const float uv = acc[k] * gf;
      const __bf16 ub = (__bf16)uv;
      u_buf[(size_t)(b*KS + k)*DD + tid] = __builtin_bit_cast(unsigned short, ub);
      sus[k] = uv;
      cbs[k] = acc[k] * bfv;
    }
    #pragma unroll
    for (int k = 0; k < KS; ++k) {
      float s = sus[k], cv = cbs[k];
      #pragma unroll
      for (int m = 1; m < 64; m <<= 1) { s += __shfl_xor(s, m); cv += __shfl_xor(cv, m); }
      if (lane == 0) { redsu[w][k] = s; redcb[w][k] = cv; }
    }
    __syncthreads();
    if (tid < KS) {
      su_buf[b*KS + tid] = redsu[0][tid]+redsu[1][tid]+redsu[2][tid]+redsu[3][tid];
      cb_buf[b*KS + tid] = redcb[0][tid]+redcb[1][tid]+redcb[2][tid]+redcb[3][tid];
    }
  }
}

// ---------------------------------------------------------------- big fused attention pass
__launch_bounds__(256, 2)
__global__ void big_attn_kernel(const float* __restrict__ feat,
                                const unsigned short* __restrict__ u_buf,
                                const float* __restrict__ su_buf,
                                const float* __restrict__ cb_buf,
                                float* __restrict__ P_part,
                                float* __restrict__ S_part,
                                float* __restrict__ R_part,
                                float* __restrict__ attn_out,
                                int last)
{
  __shared__ unsigned int xl[4][128*36];   // per-wave pair-packed col-major x tile
  __shared__ float ssh[4][16];
  __shared__ float rsh[4][16];

  const int b   = blockIdx.x / NBLK;
  const int blk = blockIdx.x - b*NBLK;
  const int tid = threadIdx.x;
  const int w = tid >> 6;
  const int l = tid & 63;
  const int c = l & 15;
  const int g = l >> 4;

  // u fragments held in registers: ufrag[kk][j] = u[slot=c][feat=32*kk+8*g+j]
  bf16x8 ufrag[8];
  {
    const bf16x8* up = reinterpret_cast<const bf16x8*>(u_buf + (size_t)(b*KS + c)*FEATN);
    #pragma unroll
    for (int kk = 0; kk < 8; ++kk) ufrag[kk] = up[4*kk + g];
  }
  const float su_c = su_buf[b*KS + c];
  const float cb_c = cb_buf[b*KS + c];

  float4v Pacc[16];
  #pragma unroll
  for (int t = 0; t < 16; ++t) Pacc[t] = (float4v){0.f,0.f,0.f,0.f};
  float S_acc = 0.f, R_acc = 0.f;

  unsigned int* myxl = xl[w];
  const int rbase = 8*(c>>2) + (c&3);   // interleaved row map: n_local = 8*(rho>>2)+4*tp+(rho&3)

  for (int pass = 0; pass < 4; ++pass) {
    const int n0 = blk*(NTOK/NBLK) + pass*128 + w*32;
    float4v Ct[2];
    float m_t[2], rs_t[2];

    #pragma unroll
    for (int tp = 0; tp < 2; ++tp) {
      const int nloc = rbase + 4*tp;
      const float* fr = feat + ((size_t)b*NTOK + (size_t)(n0 + nloc))*FEATN;
      float sum = 0.f, sq = 0.f;
      float4v Cacc = (float4v){0.f,0.f,0.f,0.f};
      #pragma unroll
      for (int kk = 0; kk < 8; ++kk) {
        const float4v x0 = *reinterpret_cast<const float4v*>(fr + 32*kk + 8*g);
        const float4v x1 = *reinterpret_cast<const float4v*>(fr + 32*kk + 8*g + 4);
        sum += x0[0]+x0[1]+x0[2]+x0[3] + x1[0]+x1[1]+x1[2]+x1[3];
        sq  += x0[0]*x0[0]+x0[1]*x0[1]+x0[2]*x0[2]+x0[3]*x0[3]
             + x1[0]*x1[0]+x1[1]*x1[1]+x1[2]*x1[2]+x1[3]*x1[3];
        bf16x8 af;
        af[0]=(__bf16)x0[0]; af[1]=(__bf16)x0[1]; af[2]=(__bf16)x0[2]; af[3]=(__bf16)x0[3];
        af[4]=(__bf16)x1[0]; af[5]=(__bf16)x1[1]; af[6]=(__bf16)x1[2]; af[7]=(__bf16)x1[3];
        const uint4v ad = __builtin_bit_cast(uint4v, af);
        // col-major pair store: pair p = 16*kk+4*g+i holds (d=2p, d=2p+1) of row nloc
        const int pb = (16*kk + 4*g)*36 + nloc;
        myxl[pb      ] = ad[0];
        myxl[pb + 36 ] = ad[1];
        myxl[pb + 72 ] = ad[2];
        myxl[pb + 108] = ad[3];
        Cacc = __builtin_amdgcn_mfma_f32_16x16x32_bf16(af, ufrag[kk], Cacc, 0, 0, 0);
      }
      sum += __shfl_xor(sum,16); sum += __shfl_xor(sum,32);
      sq  += __shfl_xor(sq ,16); sq  += __shfl_xor(sq ,32);
      const float mean = sum * (1.f/FEATN);
      const float var  = sq  * (1.f/FEATN) - mean*mean;
      m_t[tp]  = mean;
      rs_t[tp] = rsqrtf(var + LN_EPS);
      Ct[tp]   = Cacc;
    }

    float arr[8];  // a*rs in P-MFMA A-fragment j-order (j = 4*tp + r)
    #pragma unroll
    for (int tp = 0; tp < 2; ++tp) {
      float lv[4], rsr[4], mr[4];
      #pragma unroll
      for (int r = 0; r < 4; ++r) {
        const int src = 4*g + r;              // stats of row n0+8g+4tp+r live at lane (4g+r)
        rsr[r] = __shfl(rs_t[tp], src);
        mr[r]  = __shfl(m_t[tp],  src);
        lv[r]  = 0.0625f * (rsr[r]*(Ct[tp][r] - mr[r]*su_c) + cb_c);
      }
      float a_[4];
      #pragma unroll
      for (int r = 0; r < 4; ++r) {
        float v = lv[r];
        v = fmaxf(v, __shfl_xor(v,1));
        v = fmaxf(v, __shfl_xor(v,2));
        v = fmaxf(v, __shfl_xor(v,4));
        v = fmaxf(v, __shfl_xor(v,8));
        const float e = __expf(lv[r] - v);
        float s = e;
        s += __shfl_xor(s,1);
        s += __shfl_xor(s,2);
        s += __shfl_xor(s,4);
        s += __shfl_xor(s,8);
        const float a = e / s;
        a_[r] = a;
        S_acc += a;
        R_acc += a * rsr[r] * mr[r];
        arr[4*tp + r] = a * rsr[r];
      }
      if (last) {
        float4v av = {a_[0], a_[1], a_[2], a_[3]};
        *reinterpret_cast<float4v*>(attn_out + (size_t)(b*KS + c)*NTOK + (size_t)(n0 + 8*g + 4*tp)) = av;
      }
    }
    bf16x8 afrag;
    #pragma unroll
    for (int j = 0; j < 8; ++j) afrag[j] = (__bf16)arr[j];

    // P[k][d] += sum_n a_rs[k][n] * x[n][d]  over 16 d-tiles
    #pragma unroll
    for (int t = 0; t < 16; ++t) {
      const unsigned int* rp = &myxl[(t*8 + (c>>1))*36 + 8*g];
      const uint4v q0 = *reinterpret_cast<const uint4v*>(rp);
      const uint4v q1 = *reinterpret_cast<const uint4v*>(rp + 4);
      const unsigned int sel = (c & 1) ? 0x07060302u : 0x05040100u;
      uint4v bd;
      bd[0] = __builtin_amdgcn_perm(q0[1], q0[0], sel);
      bd[1] = __builtin_amdgcn_perm(q0[3], q0[2], sel);
      bd[2] = __builtin_amdgcn_perm(q1[1], q1[0], sel);
      bd[3] = __builtin_amdgcn_perm(q1[3], q1[2], sel);
      const bf16x8 bfrag = __builtin_bit_cast(bf16x8, bd);
      Pacc[t] = __builtin_amdgcn_mfma_f32_16x16x32_bf16(afrag, bfrag, Pacc[t], 0, 0, 0);
    }
  }

  S_acc += __shfl_xor(S_acc,16); S_acc += __shfl_xor(S_acc,32);
  R_acc += __shfl_xor(R_acc,16); R_acc += __shfl_xor(R_acc,32);
  if (g == 0) { ssh[w][c] = S_acc; rsh[w][c] = R_acc; }

  // dump per-wave P to (own) LDS region, then block-combine
  float* pf = reinterpret_cast<float*>(xl[w]);
  #pragma unroll
  for (int t = 0; t < 16; ++t) {
    #pragma unroll
    for (int r = 0; r < 4; ++r) pf[(4*g + r)*256 + t*16 + c] = Pacc[t][r];
  }
  __syncthreads();
  {
    float* outp = P_part + (size_t)blockIdx.x * (KS*DD);
    const float* p0 = reinterpret_cast<const float*>(xl[0]);
    const float* p1 = reinterpret_cast<const float*>(xl[1]);
    const float* p2 = reinterpret_cast<const float*>(xl[2]);
    const float* p3 = reinterpret_cast<const float*>(xl[3]);
    for (int i = tid; i < KS*DD; i += 256) outp[i] = p0[i]+p1[i]+p2[i]+p3[i];
    if (tid < KS) {
      S_part[blockIdx.x*KS + tid] = ssh[0][tid]+ssh[1][tid]+ssh[2][tid]+ssh[3][tid];
      R_part[blockIdx.x*KS + tid] = rsh[0][tid]+rsh[1][tid]+rsh[2][tid]+rsh[3][tid];
    }
  }
}

// ---------------------------------------------------------------- reduce partials + Wv GEMV
__global__ void red_upd_kernel(const float* __restrict__ P_part,
                               const float* __restrict__ S_part,
                               const float* __restrict__ R_part,
                               const float* __restrict__ g_f, const float* __restrict__ b_f,
                               const float* __restrict__ Wv,
                               float* __restrict__ upd)
{
  const int b = blockIdx.x, tid = threadIdx.x;
  __shared__ float T[KS][DD];
  __shared__ float Ssh[KS], Rsh[KS];
  if (tid < KS) {
    float S = 0.f, R = 0.f;
    for (int p = 0; p < NBLK; ++p) {
      S += S_part[(b*NBLK + p)*KS + tid];
      R += R_part[(b*NBLK + p)*KS + tid];
    }
    Ssh[tid] = S; Rsh[tid] = R;
  }
  __syncthreads();
  const float gf = g_f[tid], bfv = b_f[tid];
  for (int k = 0; k < KS; ++k) {
    float P = 0.f;
    for (int p = 0; p < NBLK; ++p)
      P += P_part[((size_t)(b*NBLK + p)*KS + k)*DD + tid];
    const float S = Ssh[k], R = Rsh[k];
    T[k][tid] = (gf*(P - R) + S*bfv) / (S + 1.0f);
  }
  __syncthreads();
  float acc[KS];
  #pragma unroll
  for (int k = 0; k < KS; ++k) acc[k] = 0.f;
  for (int cc = 0; cc < DD; ++cc) {
    const float wv = Wv[(size_t)tid*DD + cc];
    #pragma unroll
    for (int k = 0; k < KS; ++k) acc[k] += T[k][cc] * wv;
  }
  #pragma unroll
  for (int k = 0; k < KS; ++k) upd[(size_t)(b*KS + k)*DD + tid] = acc[k];
}

// ---------------------------------------------------------------- GRU gate GEMVs
__global__ void gru_gemv_kernel(const float* __restrict__ upd,
                                const float* __restrict__ slots,
                                const float* __restrict__ w_ih, const float* __restrict__ w_hh,
                                const float* __restrict__ b_ih, const float* __restrict__ b_hh,
                                float* __restrict__ gi_buf, float* __restrict__ gh_buf)
{
  const int b = blockIdx.x / 12, jo = blockIdx.x % 12;
  const int tid = threadIdx.x;
  const int jl = tid & 63, kg = tid >> 6;
  const int j = jo*64 + jl;
  __shared__ float X[KS][DD];
  __shared__ float H[KS][DD];
  for (int i = tid; i < KS*DD; i += 256) {
    X[i>>8][i&255] = upd[(size_t)b*KS*DD + i];
    H[i>>8][i&255] = slots[(size_t)b*KS*DD + i];
  }
  __syncthreads();
  float gi[4], gh[4];
  const float bi = b_ih[j], bh = b_hh[j];
  #pragma unroll
  for (int q = 0; q < 4; ++q) { gi[q] = bi; gh[q] = bh; }
  for (int cc = 0; cc < DD; ++cc) {
    const float wi = w_ih[(size_t)j*DD + cc];
    const float wh = w_hh[(size_t)j*DD + cc];
    #pragma unroll
    for (int q = 0; q < 4; ++q) {
      const int k = kg*4 + q;
      gi[q] += X[k][cc]*wi;
      gh[q] += H[k][cc]*wh;
    }
  }
  #pragma unroll
  for (int q = 0; q < 4; ++q) {
    const int k = kg*4 + q;
    gi_buf[(size_t)(b*KS + k)*768 + j] = gi[q];
    gh_buf[(size_t)(b*KS + k)*768 + j] = gh[q];
  }
}

// ---------------------------------------------------------------- GRU combine + LN
__global__ void gru_comb_kernel(const float* __restrict__ gi_buf,
                                const float* __restrict__ gh_buf,
                                const float* __restrict__ slots,
                                const float* __restrict__ g_m, const float* __restrict__ b_m,
                                float* __restrict__ hprime, float* __restrict__ y2)
{
  const int bk = blockIdx.x, tid = threadIdx.x;
  const int w = tid >> 6, lane = tid & 63;
  __shared__ float red[8];
  const float* gi = gi_buf + (size_t)bk*768;
  const float* gh = gh_buf + (size_t)bk*768;
  const float h = slots[(size_t)bk*DD + tid];
  const float r = 1.f/(1.f + __expf(-(gi[tid]       + gh[tid])));
  const float z = 1.f/(1.f + __expf(-(gi[256 + tid] + gh[256 + tid])));
  const float n = tanhf(gi[512 + tid] + r*gh[512 + tid]);
  const float hp = (1.f - z)*n + z*h;
  hprime[(size_t)bk*DD + tid] = hp;
  float s = hp;
  #pragma unroll
  for (int m = 1; m < 64; m <<= 1) s += __shfl_xor(s, m);
  if (lane == 0) red[w] = s;
  __syncthreads();
  const float mean = (red[0]+red[1]+red[2]+red[3]) * (1.f/DD);
  const float dv = hp - mean;
  float s2 = dv*dv;
  #pragma unroll
  for (int m = 1; m < 64; m <<= 1) s2 += __shfl_xor(s2, m);
  if (lane == 0) red[4+w] = s2;
  __syncthreads();
  const float var = (red[4]+red[5]+red[6]+red[7]) * (1.f/DD);
  y2[(size_t)bk*DD + tid] = dv * rsqrtf(var + LN_EPS) * g_m[tid] + b_m[tid];
}

// ---------------------------------------------------------------- MLP
__global__ void mlp1_kernel(const float* __restrict__ y2,
                            const float* __restrict__ W1, const float* __restrict__ b1,
                            float* __restrict__ hid)
{
  const int b = blockIdx.x >> 4, jo = blockIdx.x & 15;
  const int tid = threadIdx.x;
  const int jl = tid & 63, kg = tid >> 6;
  const int j = jo*64 + jl;
  __shared__ float Y[KS][DD];
  for (int i = tid; i < KS*DD; i += 256) Y[i>>8][i&255] = y2[(size_t)b*KS*DD + i];
  __syncthreads();
  float acc[4];
  const float bb = b1[j];
  #pragma unroll
  for (int q = 0; q < 4; ++q) acc[q] = bb;
  for (int cc = 0; cc < DD; ++cc) {
    const float wv = W1[(size_t)j*DD + cc];
    #pragma unroll
    for (int q = 0; q < 4; ++q) acc[q] += Y[kg*4 + q][cc] * wv;
  }
  #pragma unroll
  for (int q = 0; q < 4; ++q)
    hid[(size_t)(b*KS + kg*4 + q)*1024 + j] = fmaxf(acc[q], 0.f);
}

__global__ void mlp2_kernel(const float* __restrict__ hid,
                            const float* __restrict__ W2, const float* __restrict__ b2,
                            const float* __restrict__ hprime,
                            float* __restrict__ slots_out, float* __restrict__ dout_slots,
                            int last)
{
  const int b = blockIdx.x >> 2, dd = blockIdx.x & 3;
  const int tid = threadIdx.x;
  const int dl = tid & 63, kg = tid >> 6;
  const int d = dd*64 + dl;
  __shared__ float Hd[KS][1024];
  for (int i = tid; i < KS*1024; i += 256) Hd[i>>10][i&1023] = hid[(size_t)b*KS*1024 + i];
  __syncthreads();
  float acc[4];
  const float bb = b2[d];
  #pragma unroll
  for (int q = 0; q < 4; ++q) acc[q] = bb;
  for (int jj = 0; jj < 1024; ++jj) {
    const float wv = W2[(size_t)d*1024 + jj];
    #pragma unroll
    for (int q = 0; q < 4; ++q) acc[q] += Hd[kg*4 + q][jj] * wv;
  }
  #pragma unroll
  for (int q = 0; q < 4; ++q) {
    const int k = kg*4 + q;
    const float v = hprime[(size_t)(b*KS + k)*DD + d] + acc[q];
    slots_out[(size_t)(b*KS + k)*DD + d] = v;
    if (last) dout_slots[(size_t)(b*KS + k)*DD + d] = v;
  }
}

// ---------------------------------------------------------------- host
extern "C" void kernel_launch(void* const* d_in, const int* in_sizes, int n_in,
                              void* d_out, int out_size, void* d_ws, size_t ws_size,
                              hipStream_t stream)
{
  const float* features   = (const float*)d_in[0];
  const float* slots_init = (const float*)d_in[1];
  const float* g_f = (const float*)d_in[2];
  const float* b_f = (const float*)d_in[3];
  const float* g_s = (const float*)d_in[4];
  const float* b_s = (const float*)d_in[5];
  const float* g_m = (const float*)d_in[6];
  const float* b_m = (const float*)d_in[7];
  const float* Wq  = (const float*)d_in[8];
  const float* Wk  = (const float*)d_in[9];
  const float* Wv  = (const float*)d_in[10];
  const float* w_ih = (const float*)d_in[11];
  const float* w_hh = (const float*)d_in[12];
  const float* b_ih = (const float*)d_in[13];
  const float* b_hh = (const float*)d_in[14];
  const float* W1  = (const float*)d_in[15];
  const float* b1  = (const float*)d_in[16];
  const float* W2  = (const float*)d_in[17];
  const float* b2  = (const float*)d_in[18];

  float* out_slots = (float*)d_out;
  float* out_attn  = out_slots + (size_t)BB*KS*DD;

  char* ws = (char*)d_ws;
  size_t off = 0;
  auto alloc = [&](size_t bytes) -> void* {
    void* p = ws + off;
    off += (bytes + 255) & ~(size_t)255;
    return p;
  };
  float*          slots_cur = (float*)alloc((size_t)BB*KS*DD*4);
  unsigned short* u_buf     = (unsigned short*)alloc((size_t)BB*KS*DD*2);
  float*          su_buf    = (float*)alloc((size_t)BB*KS*4);
  float*          cb_buf    = (float*)alloc((size_t)BB*KS*4);
  float*          P_part    = (float*)alloc((size_t)BB*NBLK*KS*DD*4);
  float*          S_part    = (float*)alloc((size_t)BB*NBLK*KS*4);
  float*          R_part    = (float*)alloc((size_t)BB*NBLK*KS*4);
  float*          upd       = (float*)alloc((size_t)BB*KS*DD*4);
  float*          gi_buf    = (float*)alloc((size_t)BB*KS*768*4);
  float*          gh_buf    = (float*)alloc((size_t)BB*KS*768*4);
  float*          hprime    = (float*)alloc((size_t)BB*KS*DD*4);
  float*          y2        = (float*)alloc((size_t)BB*KS*DD*4);
  float*          hid       = (float*)alloc((size_t)BB*KS*1024*4);
  (void)in_sizes; (void)n_in; (void)out_size; (void)ws_size;

  hipMemcpyAsync(slots_cur, slots_init, (size_t)BB*KS*DD*4, hipMemcpyDeviceToDevice, stream);

  for (int it = 0; it < 3; ++it) {
    const int last = (it == 2);
    stage0_kernel<<<BB, 256, 0, stream>>>(slots_cur, Wq, Wk, g_s, b_s, g_f, b_f,
                                          u_buf, su_buf, cb_buf);
    big_attn_kernel<<<BB*NBLK, 256, 0, stream>>>(features, u_buf, su_buf, cb_buf,
                                                 P_part, S_part, R_part, out_attn, last);
    red_upd_kernel<<<BB, 256, 0, stream>>>(P_part, S_part, R_part, g_f, b_f, Wv, upd);
    gru_gemv_kernel<<<BB*12, 256, 0, stream>>>(upd, slots_cur, w_ih, w_hh, b_ih, b_hh,
                                               gi_buf, gh_buf);
    gru_comb_kernel<<<BB*KS, 256, 0, stream>>>(gi_buf, gh_buf, slots_cur, g_m, b_m,
                                               hprime, y2);
    mlp1_kernel<<<BB*16, 256, 0, stream>>>(y2, W1, b1, hid);
    mlp2_kernel<<<BB*4, 256, 0, stream>>>(hid, W2, b2, hprime, slots_cur, out_slots, last);
  }
}